// Round 4
// baseline (4931.762 us; speedup 1.0000x reference)
//
#include <hip/hip_runtime.h>
#include <hip/hip_fp16.h>

// FPS: B=64 clouds, M=16384 pts/cloud, K=4096 selections. int32 output.
// One workgroup/cloud, 1024 threads, 16 pts/thread in VGPRs.
// Round-4 fixes: (1) amdgpu_waves_per_eu(4,4) raises the VGPR cap to 128 so
// the pinned coord arrays actually stay register-resident (round 3 spilled:
// VGPR_Count=52 < 80 live floats). (2) winner-coord fetch from a 96 KB LDS
// f16 table (~80 cyc broadcast) instead of uniform L2 loads (~250 cyc).
// e-form update: e[j] = min(e[j], |s|^2 - 2 p.s), d = e + |p|^2 for argmax.

#define NCLOUDS 64
#define M 16384
#define KSEL 4096
#define NT 1024
#define PPT 16                   // M / NT
#define IDXMASK   0x3FFFu        // 14-bit in-cloud index
#define TRUNCMASK 0x7FFFC000u    // 17 bits of fp32 dist (sign cleared)
#define JMASK     0x7FFFFFF0u    // 27 bits of fp32 dist | 4-bit j

static __device__ __forceinline__ unsigned int umax_(unsigned int a, unsigned int b) {
    return a > b ? a : b;
}

// One DPP max step; invalid (shifted-in) lanes contribute 0.
template <int CTRL>
static __device__ __forceinline__ unsigned int dpp_max(unsigned int v) {
    unsigned int s = (unsigned int)__builtin_amdgcn_update_dpp(
        0, (int)v, CTRL, 0xF, 0xF, false);
    return umax_(v, s);
}

// 64-lane max; result valid in lane 63 (row_shr 1/2/4/8, bcast15, bcast31).
static __device__ __forceinline__ unsigned int wave_max63(unsigned int v) {
    v = dpp_max<0x111>(v);
    v = dpp_max<0x112>(v);
    v = dpp_max<0x114>(v);
    v = dpp_max<0x118>(v);
    v = dpp_max<0x142>(v);
    v = dpp_max<0x143>(v);
    return v;
}

__global__ __launch_bounds__(NT) __attribute__((amdgpu_waves_per_eu(4, 4)))
void fps_kernel(const float* __restrict__ pos, int* __restrict__ out) {
    const int b    = blockIdx.x;
    const int t    = threadIdx.x;
    const int wid  = t >> 6;
    const int lane = t & 63;

    __shared__ unsigned int sxy[M];        // packed f16x2 (x,y): 64 KB
    __shared__ __half       szl[M];        // f16 z: 32 KB
    __shared__ unsigned int skey[2][16];   // double-buffered wave partials

    const float* __restrict__ cloud = pos + (size_t)b * (M * 3);
    int* __restrict__ outb = out + (size_t)b * KSEL;

    // ---- prologue: load coords, build LDS f16 table, pin registers ----
    float px[PPT], py[PPT], pz[PPT], pp[PPT], e[PPT];
#pragma unroll
    for (int j = 0; j < PPT; ++j) {
        const int i = j * NT + t;
        px[j] = cloud[i * 3 + 0];
        py[j] = cloud[i * 3 + 1];
        pz[j] = cloud[i * 3 + 2];
        pp[j] = px[j] * px[j] + py[j] * py[j] + pz[j] * pz[j];
        __half2 h2 = __floats2half2_rn(px[j], py[j]);
        sxy[i] = *reinterpret_cast<unsigned int*>(&h2);
        szl[i] = __float2half_rn(pz[j]);
        asm volatile("" : "+v"(px[j]), "+v"(py[j]), "+v"(pz[j]), "+v"(pp[j]));
    }

    // first sample: local index 0 (random_first=False); exact f32 coords
    float wx = cloud[0], wy = cloud[1], wz = cloud[2];
    if (t == 0) outb[0] = b * M;
    float sww = wx * wx + wy * wy + wz * wz;

    unsigned int key[4] = {0u, 0u, 0u, 0u};
#pragma unroll
    for (int j = 0; j < PPT; ++j) {
        float dot = px[j] * wx;
        dot = __builtin_fmaf(py[j], wy, dot);
        dot = __builtin_fmaf(pz[j], wz, dot);
        e[j] = __builtin_fmaf(dot, -2.0f, sww);
        const unsigned int kk =
            (__float_as_uint(e[j] + pp[j]) & JMASK) | (unsigned int)j;
        key[j & 3] = umax_(key[j & 3], kk);
    }

    for (int k = 1; k < KSEL; ++k) {
        // per-thread key -> block key (17-bit dist | 14-bit idx)
        unsigned int tk = umax_(umax_(key[0], key[1]), umax_(key[2], key[3]));
        const unsigned int jj = tk & 15u;
        tk = (tk & TRUNCMASK) | ((unsigned int)t + (jj << 10));

        tk = wave_max63(tk);
        const int buf = k & 1;
        if (lane == 63) skey[buf][wid] = tk;
        __syncthreads();   // single barrier per iteration

        unsigned int g = skey[buf][lane & 15];
        g = dpp_max<0x111>(g);
        g = dpp_max<0x112>(g);
        g = dpp_max<0x114>(g);
        g = dpp_max<0x118>(g);
        const unsigned int gmax = (unsigned int)__builtin_amdgcn_readlane((int)g, 15);

        const int wi = (int)(gmax & IDXMASK);
        if (t == 0) outb[k] = b * M + wi;

        // winner coords: LDS broadcast read (f16), consistent across threads
        const unsigned int wxy = sxy[wi];
        const float2 f2 = __half22float2(*reinterpret_cast<const __half2*>(&wxy));
        wx = f2.x;
        wy = f2.y;
        wz = __half2float(szl[wi]);
        sww = wx * wx + wy * wy + wz * wz;

        // fused min-update + per-thread argmax (8 VALU/pt)
        key[0] = key[1] = key[2] = key[3] = 0u;
#pragma unroll
        for (int j = 0; j < PPT; ++j) {
            float dot = px[j] * wx;
            dot = __builtin_fmaf(py[j], wy, dot);
            dot = __builtin_fmaf(pz[j], wz, dot);
            const float cand = __builtin_fmaf(dot, -2.0f, sww);
            e[j] = fminf(e[j], cand);
            const unsigned int kk =
                (__float_as_uint(e[j] + pp[j]) & JMASK) | (unsigned int)j;
            key[j & 3] = umax_(key[j & 3], kk);
        }
    }
}

extern "C" void kernel_launch(void* const* d_in, const int* in_sizes, int n_in,
                              void* d_out, int out_size, void* d_ws, size_t ws_size,
                              hipStream_t stream) {
    const float* pos = (const float*)d_in[0];
    // d_in[1] (batch) is uniform B x M — unused.
    int* out = (int*)d_out;
    fps_kernel<<<dim3(NCLOUDS), dim3(NT), 0, stream>>>(pos, out);
}

// Round 6
// 3683.589 us; speedup vs baseline: 1.3388x; 1.3388x over previous
//
#include <hip/hip_runtime.h>
#include <hip/hip_fp16.h>
#include <string.h>

// FPS: B=64 clouds, M=16384 pts, K=4096 selections. int32 output.
// One workgroup/cloud, 1024 threads, 16 pts/thread packed as 8 x f16x2.
// Theory: rounds 2-4 were VALU-bound because the allocator parked ~84 f32
// live values in AGPRs (VGPR_Count=52 << live set; v_accvgpr moves doubled
// VALU work). Fix: f16x2-packed coords+dists -> ~45 live VGPRs and packed
// v_pk_* math halves the update ops. ROCm 7.2 lacks __hmax2/__hmin2, so
// packed max/min are inline-asm v_pk_max_f16 / v_pk_min_f16 on u32.
// Argmax: truncate low 4 mantissa bits of each f16 dist, embed 4-bit slot
// c; winner local index = (c<<10)|t. Winner coords via 96 KB LDS f16 table.

#define NCLOUDS 64
#define M 16384
#define KSEL 4096
#define NT 1024
#define NPAIR 8
#define IDXMASK 0x3FFFu

static __device__ __forceinline__ unsigned int umax_(unsigned int a, unsigned int b) {
    return a > b ? a : b;
}

// Packed f16 max/min (ROCm headers lack __hmax2/__hmin2).
static __device__ __forceinline__ unsigned int pkmax(unsigned int a, unsigned int b) {
    unsigned int d;
    asm("v_pk_max_f16 %0, %1, %2" : "=v"(d) : "v"(a), "v"(b));
    return d;
}
static __device__ __forceinline__ unsigned int pkmin(unsigned int a, unsigned int b) {
    unsigned int d;
    asm("v_pk_min_f16 %0, %1, %2" : "=v"(d) : "v"(a), "v"(b));
    return d;
}

template <int CTRL>
static __device__ __forceinline__ unsigned int dpp_max(unsigned int v) {
    unsigned int s = (unsigned int)__builtin_amdgcn_update_dpp(
        0, (int)v, CTRL, 0xF, 0xF, false);
    return umax_(v, s);
}

// 64-lane max; valid in lane 63 (row_shr 1/2/4/8, bcast15, bcast31).
static __device__ __forceinline__ unsigned int wave_max63(unsigned int v) {
    v = dpp_max<0x111>(v);
    v = dpp_max<0x112>(v);
    v = dpp_max<0x114>(v);
    v = dpp_max<0x118>(v);
    v = dpp_max<0x142>(v);
    v = dpp_max<0x143>(v);
    return v;
}

static __device__ __forceinline__ __half2 u2h(unsigned int u) {
    __half2 h; memcpy(&h, &u, 4); return h;
}
static __device__ __forceinline__ unsigned int h2u(__half2 h) {
    unsigned int u; memcpy(&u, &h, 4); return u;
}
static __device__ __forceinline__ __half2 dup16(unsigned int u) {
    return u2h((u & 0xffffu) | (u << 16));
}

__global__ __launch_bounds__(NT)
void fps_kernel(const float* __restrict__ pos, int* __restrict__ out) {
    const int b = blockIdx.x, t = threadIdx.x, wid = t >> 6, lane = t & 63;

    __shared__ unsigned int   sxy[M];      // f16 x | f16 y<<16 per point: 64 KB
    __shared__ unsigned short szt[M];      // f16 z per point: 32 KB
    __shared__ unsigned int   skey[2][16]; // double-buffered wave partials

    const float* __restrict__ cloud = pos + (size_t)b * (M * 3);
    int* __restrict__ outb = out + (size_t)b * KSEL;

    // Layout: local point i = c*NT + t, c in [0,16); pair j = slots (2j, 2j+1).
    unsigned int hx[NPAIR], hy[NPAIR], hz[NPAIR], hd[NPAIR];

#pragma unroll
    for (int j = 0; j < NPAIR; ++j) {
        const int i0 = (2 * j) * NT + t;
        const int i1 = (2 * j + 1) * NT + t;
        const float x0 = cloud[i0 * 3 + 0], y0 = cloud[i0 * 3 + 1], z0 = cloud[i0 * 3 + 2];
        const float x1 = cloud[i1 * 3 + 0], y1 = cloud[i1 * 3 + 1], z1 = cloud[i1 * 3 + 2];
        hx[j] = h2u(__halves2half2(__float2half_rn(x0), __float2half_rn(x1)));
        hy[j] = h2u(__halves2half2(__float2half_rn(y0), __float2half_rn(y1)));
        hz[j] = h2u(__halves2half2(__float2half_rn(z0), __float2half_rn(z1)));
        sxy[i0] = (hx[j] & 0xffffu) | ((hy[j] & 0xffffu) << 16);
        sxy[i1] = (hx[j] >> 16) | (hy[j] & 0xffff0000u);
        szt[i0] = (unsigned short)(hz[j] & 0xffffu);
        szt[i1] = (unsigned short)(hz[j] >> 16);
        asm volatile("" : "+v"(hx[j]), "+v"(hy[j]), "+v"(hz[j]));
    }

    // First sample: local index 0 (random_first=False).
    __half2 wx2 = __half2half2(__float2half_rn(cloud[0]));
    __half2 wy2 = __half2half2(__float2half_rn(cloud[1]));
    __half2 wz2 = __half2half2(__float2half_rn(cloud[2]));
    if (t == 0) outb[0] = b * M;

    unsigned int mkA = 0u, mkB = 0u;   // packed running argmax keys (2-way ILP)
#pragma unroll
    for (int j = 0; j < NPAIR; ++j) {
        __half2 dx = __hsub2(u2h(hx[j]), wx2);
        __half2 dy = __hsub2(u2h(hy[j]), wy2);
        __half2 dz = __hsub2(u2h(hz[j]), wz2);
        __half2 s2 = __hmul2(dx, dx);
        s2 = __hfma2(dy, dy, s2);
        s2 = __hfma2(dz, dz, s2);
        hd[j] = h2u(s2);
        const unsigned int orc = (unsigned int)(2 * j) | ((unsigned int)(2 * j + 1) << 16);
        const unsigned int kk = (hd[j] & 0xFFF0FFF0u) | orc;
        if (j & 1) mkB = pkmax(mkB, kk);
        else       mkA = pkmax(mkA, kk);
    }

    for (int k = 1; k < KSEL; ++k) {
        // per-thread fold: packed keys -> scalar key (12-bit dist | c | t)
        const unsigned int mk = pkmax(mkA, mkB);
        const unsigned int mv = umax_(mk >> 16, mk & 0xffffu);
        unsigned int key = ((mv & 0xFFF0u) << 14) | ((mv & 0xFu) << 10) | (unsigned int)t;

        key = wave_max63(key);
        const int buf = k & 1;
        if (lane == 63) skey[buf][wid] = key;
        __syncthreads();   // single barrier per iteration

        unsigned int g = skey[buf][lane & 15];
        g = dpp_max<0x111>(g);
        g = dpp_max<0x112>(g);
        g = dpp_max<0x114>(g);
        g = dpp_max<0x118>(g);
        const unsigned int gmax = (unsigned int)__builtin_amdgcn_readlane((int)g, 15);

        const int wi = (int)(gmax & IDXMASK);
        if (t == 0) outb[k] = b * M + wi;

        // winner coords: LDS broadcast (f16), identical across all threads
        const unsigned int wxy = sxy[wi];
        const unsigned int uzz = (unsigned int)szt[wi];
        wx2 = dup16(wxy);
        wy2 = dup16(wxy >> 16);
        wz2 = dup16(uzz);

        // fused packed min-update + argmax key tracking (9 pk-ops/pair)
        mkA = 0u; mkB = 0u;
#pragma unroll
        for (int j = 0; j < NPAIR; ++j) {
            __half2 dx = __hsub2(u2h(hx[j]), wx2);
            __half2 dy = __hsub2(u2h(hy[j]), wy2);
            __half2 dz = __hsub2(u2h(hz[j]), wz2);
            __half2 s2 = __hmul2(dx, dx);
            s2 = __hfma2(dy, dy, s2);
            s2 = __hfma2(dz, dz, s2);
            hd[j] = pkmin(hd[j], h2u(s2));
            const unsigned int orc = (unsigned int)(2 * j) | ((unsigned int)(2 * j + 1) << 16);
            const unsigned int kk = (hd[j] & 0xFFF0FFF0u) | orc;  // v_and_or_b32
            if (j & 1) mkB = pkmax(mkB, kk);
            else       mkA = pkmax(mkA, kk);
        }
    }
}

extern "C" void kernel_launch(void* const* d_in, const int* in_sizes, int n_in,
                              void* d_out, int out_size, void* d_ws, size_t ws_size,
                              hipStream_t stream) {
    const float* pos = (const float*)d_in[0];
    // d_in[1] (batch) is uniform B x M — unused.
    int* out = (int*)d_out;
    fps_kernel<<<dim3(NCLOUDS), dim3(NT), 0, stream>>>(pos, out);
}

// Round 8
// 3262.541 us; speedup vs baseline: 1.5116x; 1.1291x over previous
//
#include <hip/hip_runtime.h>
#include <string.h>

// FPS: B=64 clouds, M=16384 pts, K=4096 selections. int32 output.
// One workgroup/cloud, 512 threads (8 waves), 32 pts/thread as 16 f16x2 pairs.
// Round-7: (1) no inline asm in the hot loop — native _Float16 vectors +
// __builtin_elementwise_min/max on ushort2 (v_pk_min_u16/v_pk_max_u16;
// uint compare == f16 compare for nonneg dists). (2) slot index permanently
// embedded in hd's low 4 bits -> update is 8 ops/pair; argmax fold (15 pkmax
// tree) hoisted out of the loop. (3) 8 waves instead of 16 halves per-wave
// overhead and barrier width. waves_per_eu(1,2) -> 256-VGPR cap, no
// AGPR-parking of the ~90-reg live set.
// Key: best16 = dist12|j4; block key = (best16<<10)|ibase, where
// i_local = (j<<10) + h*512 + t falls exactly in bits [13:0].

#define NCLOUDS 64
#define M 16384
#define KSEL 4096
#define NT 512
#define NPAIR 16
#define IDXMASK 0x3FFFu

typedef _Float16 h2 __attribute__((ext_vector_type(2)));
typedef unsigned short u16x2 __attribute__((ext_vector_type(2)));

static __device__ __forceinline__ unsigned int asu_h(h2 x) {
    return __builtin_bit_cast(unsigned int, x);
}
static __device__ __forceinline__ h2 ash(unsigned int x) {
    return __builtin_bit_cast(h2, x);
}
static __device__ __forceinline__ unsigned int asu_s(u16x2 x) {
    return __builtin_bit_cast(unsigned int, x);
}
static __device__ __forceinline__ u16x2 ass(unsigned int x) {
    return __builtin_bit_cast(u16x2, x);
}

static __device__ __forceinline__ unsigned int umax_(unsigned int a, unsigned int b) {
    return a > b ? a : b;
}
// Packed u16 min/max -> v_pk_min_u16 / v_pk_max_u16.
static __device__ __forceinline__ unsigned int pkmin_u(unsigned int a, unsigned int b) {
    return asu_s(__builtin_elementwise_min(ass(a), ass(b)));
}
static __device__ __forceinline__ unsigned int pkmax_u(unsigned int a, unsigned int b) {
    return asu_s(__builtin_elementwise_max(ass(a), ass(b)));
}

template <int CTRL>
static __device__ __forceinline__ unsigned int dpp_max(unsigned int v) {
    unsigned int s = (unsigned int)__builtin_amdgcn_update_dpp(
        0, (int)v, CTRL, 0xF, 0xF, false);
    return umax_(v, s);
}
// 64-lane max; valid in lane 63 (row_shr 1/2/4/8, bcast15, bcast31).
static __device__ __forceinline__ unsigned int wave_max63(unsigned int v) {
    v = dpp_max<0x111>(v);
    v = dpp_max<0x112>(v);
    v = dpp_max<0x114>(v);
    v = dpp_max<0x118>(v);
    v = dpp_max<0x142>(v);
    v = dpp_max<0x143>(v);
    return v;
}

static __device__ __forceinline__ unsigned int dup_lo(unsigned int u) {
    return (u & 0xffffu) | (u << 16);
}
static __device__ __forceinline__ unsigned int dup_hi(unsigned int u) {
    return (u >> 16) | (u & 0xffff0000u);
}

__global__ __launch_bounds__(NT) __attribute__((amdgpu_waves_per_eu(1, 2)))
void fps_kernel(const float* __restrict__ pos, int* __restrict__ out) {
    const int b = blockIdx.x, t = threadIdx.x, wid = t >> 6, lane = t & 63;

    __shared__ unsigned int   sxy[M];      // f16 x | f16 y<<16 per point: 64 KB
    __shared__ unsigned short szt[M];      // f16 z per point: 32 KB
    __shared__ unsigned int   skey[2][8];  // double-buffered wave partials

    const float* __restrict__ cloud = pos + (size_t)b * (M * 3);
    int* __restrict__ outb = out + (size_t)b * KSEL;

    // Point (pair j, half h) lives at local index i = (2j+h)*NT + t.
    unsigned int hx[NPAIR], hy[NPAIR], hz[NPAIR], hd[NPAIR];

#pragma unroll
    for (int j = 0; j < NPAIR; ++j) {
        const int i0 = (2 * j) * NT + t, i1 = i0 + NT;
        const float x0 = cloud[i0 * 3 + 0], y0 = cloud[i0 * 3 + 1], z0 = cloud[i0 * 3 + 2];
        const float x1 = cloud[i1 * 3 + 0], y1 = cloud[i1 * 3 + 1], z1 = cloud[i1 * 3 + 2];
        h2 vx = {(_Float16)x0, (_Float16)x1};
        h2 vy = {(_Float16)y0, (_Float16)y1};
        h2 vz = {(_Float16)z0, (_Float16)z1};
        hx[j] = asu_h(vx); hy[j] = asu_h(vy); hz[j] = asu_h(vz);
        h2 p0 = {(_Float16)x0, (_Float16)y0};
        h2 p1 = {(_Float16)x1, (_Float16)y1};
        sxy[i0] = asu_h(p0);
        sxy[i1] = asu_h(p1);
        szt[i0] = (unsigned short)(hz[j] & 0xffffu);
        szt[i1] = (unsigned short)(hz[j] >> 16);
        asm volatile("" : "+v"(hx[j]), "+v"(hy[j]), "+v"(hz[j]));
    }

    // First sample: local index 0 (random_first=False).
    const _Float16 w0x = (_Float16)cloud[0];
    const _Float16 w0y = (_Float16)cloud[1];
    const _Float16 w0z = (_Float16)cloud[2];
    h2 wx2 = {w0x, w0x}, wy2 = {w0y, w0y}, wz2 = {w0z, w0z};
    if (t == 0) outb[0] = b * M;

    // Init: hd[j] = (dist & 0xFFF0FFF0) | (j in low 4 bits of each half).
#pragma unroll
    for (int j = 0; j < NPAIR; ++j) {
        h2 dx = ash(hx[j]) - wx2;
        h2 dy = ash(hy[j]) - wy2;
        h2 dz = ash(hz[j]) - wz2;
        h2 s2 = dx * dx + dy * dy + dz * dz;
        hd[j] = (asu_h(s2) & 0xFFF0FFF0u) | ((unsigned int)j * 0x00010001u);
    }

    for (int k = 1; k < KSEL; ++k) {
        // ---- per-thread argmax fold: 15-op pkmax tree over hd ----
        unsigned int a8[8];
#pragma unroll
        for (int j = 0; j < 8; ++j) a8[j] = pkmax_u(hd[2 * j], hd[2 * j + 1]);
#pragma unroll
        for (int j = 0; j < 4; ++j) a8[j] = pkmax_u(a8[j], a8[j + 4]);
        a8[0] = pkmax_u(a8[0], a8[2]);
        a8[1] = pkmax_u(a8[1], a8[3]);
        const unsigned int mk = pkmax_u(a8[0], a8[1]);

        const unsigned int lo = mk & 0xffffu, hi = mk >> 16;
        const unsigned int best  = umax_(lo, hi);
        const unsigned int ibase = (hi > lo) ? (unsigned int)(t + NT) : (unsigned int)t;
        unsigned int key = (best << 10) | ibase;   // dist12|j4 in [25:10], i_local in [13:0]

        key = wave_max63(key);
        const int buf = k & 1;
        if (lane == 63) skey[buf][wid] = key;
        __syncthreads();   // single barrier per iteration

        unsigned int g = skey[buf][lane & 7];
        g = dpp_max<0x111>(g);
        g = dpp_max<0x112>(g);
        g = dpp_max<0x114>(g);
        const unsigned int gmax = (unsigned int)__builtin_amdgcn_readlane((int)g, 7);

        const int wi = (int)(gmax & IDXMASK);
        if (t == 0) outb[k] = b * M + wi;

        // Winner coords: LDS broadcast (f16), identical across all threads.
        const unsigned int wxy = sxy[wi];
        const unsigned int wzz = (unsigned int)szt[wi];
        wx2 = ash(dup_lo(wxy));
        wy2 = ash(dup_hi(wxy));
        wz2 = ash(dup_lo(wzz));

        // ---- fused packed min-update (8 ops/pair, slot stays embedded) ----
#pragma unroll
        for (int j = 0; j < NPAIR; ++j) {
            h2 dx = ash(hx[j]) - wx2;
            h2 dy = ash(hy[j]) - wy2;
            h2 dz = ash(hz[j]) - wz2;
            h2 s2 = dx * dx + dy * dy + dz * dz;
            const unsigned int kk =
                (asu_h(s2) & 0xFFF0FFF0u) | ((unsigned int)j * 0x00010001u);
            hd[j] = pkmin_u(hd[j], kk);
        }
    }
}

extern "C" void kernel_launch(void* const* d_in, const int* in_sizes, int n_in,
                              void* d_out, int out_size, void* d_ws, size_t ws_size,
                              hipStream_t stream) {
    const float* pos = (const float*)d_in[0];
    // d_in[1] (batch) is uniform B x M — unused.
    int* out = (int*)d_out;
    fps_kernel<<<dim3(NCLOUDS), dim3(NT), 0, stream>>>(pos, out);
}